// Round 3
// baseline (118.326 us; speedup 1.0000x reference)
//
#include <hip/hip_runtime.h>

#define NQ  12
#define DIM 4096
#define TPB 256

typedef float v2f __attribute__((ext_vector_type(2)));
typedef float v4f __attribute__((ext_vector_type(4)));

// ---------------------------------------------------------------------------
// LDS: 32768 B exactly -> 5 blocks/CU (full 160 KiB).
// Amp layout (passes 1-4): slot(e) = e ^ (((e>>5)&7)<<1)  [round-2, verified
// conflict-free empirically: conflicts ~0].
//
// NEW this round: dense global loads + LDS x-staging.
//   Old load: lane i read float4 at byte 64i+16j -> 64 cachelines PER
//   INSTRUCTION (256 line transactions/wave for the input). New: lane reads
//   f4 index F = 256j + t (1 KB dense per wave-instr, 16 lines), stages raw
//   floats to LDS, thread reads back its owned 64 B after the norm barrier.
//   Stage layout sx(F) = F ^ ((F>>3)&7) (16B slots):
//     write (F=256j+t):  quad = (t&7)^((t>>3)&7)      -> 2 lanes/quad (min)
//     read  (F=4t+j):    quad = (4(t&1)+j)^((t>>1)&7) -> 2 lanes/quad (min)
//   Norm partials at bytes 16384.. (above the 16 KB x region); the two norm
//   barriers also cover stage-write/x-read ordering -> barrier count still 5.
// ---------------------------------------------------------------------------

__device__ __forceinline__ float wave_reduce(float v) {
#pragma unroll
    for (int m = 32; m >= 1; m >>= 1) v += __shfl_xor(v, m, 64);
    return v;
}

// broadcast lane q's value to all lanes (lands in SGPR)
#define BCAST(v, q) __uint_as_float(__builtin_amdgcn_readlane(__float_as_uint(v), (q)))

// One circuit layer: unnormalized H on register-bit MC (1/sqrt2 folded into
// epilogue), then (X*RX if XGATE else RX) on bit MT where MC==1.
// ctv = (c,c), snv = (s,-s); off-diag = -i*s, so (-i*s)*z = snv * z.yx.
template <int MC, int MT, bool XGATE>
__device__ __forceinline__ void apply_layer(v2f* a, v2f ctv, v2f snv) {
#pragma unroll
    for (int i = 0; i < 16; ++i) {
        if (i & MC) continue;
        const int j = i | MC;
        const v2f t0 = a[i], t1 = a[j];
        a[i] = t0 + t1;          // v_pk_add_f32
        a[j] = t0 - t1;
    }
#pragma unroll
    for (int i = 0; i < 16; ++i) {
        if (!(i & MC) || (i & MT)) continue;   // control=1, target=0 slot
        const int j = i | MT;
        const v2f b0 = a[i], b1 = a[j];
        const v2f s0 = snv * b0.yx;            // v_pk_mul_f32
        const v2f s1 = snv * b1.yx;
        if (XGATE) {                           // X*RX = [[s, c],[c, s]]
            a[i] = ctv * b1 + s0;              // v_pk_fma_f32
            a[j] = ctv * b0 + s1;
        } else {                               // RX = [[c, s],[s, c]]
            a[i] = ctv * b0 + s1;
            a[j] = ctv * b1 + s0;
        }
    }
}

__global__ __launch_bounds__(TPB, 5) void qlayer_kernel(
        const float* __restrict__ state, const float* __restrict__ params,
        float* __restrict__ out) {
    __shared__ __align__(16) v2f amp[DIM];     // 32768 B exactly -> 5 blocks/CU
    char* const lds = (char*)amp;

    const int t = threadIdx.x;
    const int lane = t & 63;
    const long long sbase = (long long)blockIdx.x * DIM;

    // per-lane angle (lanes 0..11 hold cos/sin(theta_q/2)); broadcast via readlane
    const float th = params[lane < NQ ? lane : 0] * 0.5f;
    const float cl = cosf(th);
    const float sl = sinf(th);

    // ---- DENSE load: lane reads f4 index 256j + t (1 KB/instr packed) ----
    const float4* gp = (const float4*)(state + sbase);
    float4 xv[4];
    float ss = 0.f;
#pragma unroll
    for (int j = 0; j < 4; ++j) {
        const float4 v = gp[t + 256 * j];
        xv[j] = v;
        ss = fmaf(v.x, v.x, ss); ss = fmaf(v.y, v.y, ss);
        ss = fmaf(v.z, v.z, ss); ss = fmaf(v.w, v.w, ss);
    }
    // stage raw floats: slot sx(F) = F ^ ((F>>3)&7); F = 256j + t
    const int stbase = 16 * (t ^ ((t >> 3) & 7));
#pragma unroll
    for (int j = 0; j < 4; ++j)
        *(v4f*)(lds + stbase + (j << 12)) = (v4f){xv[j].x, xv[j].y, xv[j].z, xv[j].w};

    ss = wave_reduce(ss);
    if (lane == 0) ((float*)lds)[4096 + (t >> 6)] = ss;   // bytes 16384.. (above x)
    __syncthreads();                                       // bar1: stage+partials done
    const float* redp = (const float*)lds + 4096;
    const float nrm  = sqrtf(redp[0] + redp[1] + redp[2] + redp[3]);
    const float invd = 1.0f / (nrm + 1e-8f);

    // read OWN 64 B back: F = 4t+j -> byte = 16*((4t+j) ^ ((t>>1)&7))
    //   = [64t ^ (((t>>3)&1)<<6) | ((t>>1)&3)<<4] with per-j ADDRESS XOR (j<<4)
    const int A = (64 * t ^ (((t >> 3) & 1) << 6)) | (((t >> 1) & 3) << 4);
    float4 x4[4];
#pragma unroll
    for (int j = 0; j < 4; ++j)
        x4[j] = *(const float4*)(lds + (A ^ (j << 4)));
    __syncthreads();   // bar2: x reads + partial reads done before P1 overwrites

    // ---- encoding: re = clamp(v,-1,1); im = sign(v)*sqrt(1-re^2) ----
    // |q|^2 == 1 exactly => second normalization = 1/4096, folded into epilogue.
    v2f a[16];
#define ENC(k, xval)                                                      \
    {                                                                     \
        const float v   = (xval) * invd;                                  \
        const float re  = fminf(fmaxf(v, -1.0f), 1.0f);                   \
        const float imb = __builtin_amdgcn_sqrtf(fmaxf(1.0f - re * re, 0.f)); \
        const float im  = (v > 0.f) ? imb : ((v < 0.f) ? -imb : 0.f);     \
        v2f q; q.x = re; q.y = im;                                        \
        a[k] = q;                                                         \
    }
#pragma unroll
    for (int j = 0; j < 4; ++j) {
        const float4 xq = x4[j];
        ENC(4 * j + 0, xq.x); ENC(4 * j + 1, xq.y);
        ENC(4 * j + 2, xq.z); ENC(4 * j + 3, xq.w);
    }
#undef ENC

#define CTV(q) ({ v2f _c; _c.x = BCAST(cl, q); _c.y = _c.x; _c; })
#define SNV(q) ({ float _s = BCAST(sl, q); v2f _v; _v.x = _s; _v.y = -_s; _v; })

    // ---- pass 1: layers 0..2 on idx bits {0,1,2,3}; e = 16t + 2k + b0 ----
    apply_layer<1, 2, true>(a, CTV(0), SNV(0));
    apply_layer<2, 4, true>(a, CTV(1), SNV(1));
    apply_layer<4, 8, true>(a, CTV(2), SNV(2));
    {
        // e>>5 = t>>1; xor bits fold as byte = 128t | ((k ^ ((t>>1)&7))<<4)
        const int v1b = (t << 7) | (((t >> 1) & 7) << 4);
#pragma unroll
        for (int k = 0; k < 8; ++k) {
            v4f w; w.x = a[2 * k].x; w.y = a[2 * k].y;
            w.z = a[2 * k + 1].x; w.w = a[2 * k + 1].y;
            *(v4f*)(lds + (v1b ^ (k << 4))) = w;
        }
    }
    __syncthreads();

    // ---- pass 2: layers 3..5 on idx bits {3,4,5,6}; e = (t&7) + 8r + 128g ----
    {
        // e>>5 = (r>>2) + 4g ; slot bit3 = (r&1)^(g&1), bits1-2 ^= (r>>2)
        const int g  = t >> 3;
        const int gp2 = g & 1;
        const int baseE = ((t & 7) << 3) + (g << 10) + (gp2 << 6);        // r even
        const int baseO = ((t & 7) << 3) + (g << 10) + ((1 - gp2) << 6);  // r odd
#pragma unroll
        for (int r = 0; r < 16; ++r)
            a[r] = *(const v2f*)(lds +
                ((((r & 1) ? baseO : baseE) ^ ((r >> 2) << 4)) + ((r >> 1) << 7)));
        apply_layer<1, 2, true>(a, CTV(3), SNV(3));
        apply_layer<2, 4, true>(a, CTV(4), SNV(4));
        apply_layer<4, 8, true>(a, CTV(5), SNV(5));
#pragma unroll
        for (int r = 0; r < 16; ++r)
            *(v2f*)(lds +
                ((((r & 1) ? baseO : baseE) ^ ((r >> 2) << 4)) + ((r >> 1) << 7))) = a[r];
    }
    __syncthreads();

    // ---- pass 3: layers 6..8 on idx bits {6,7,8,9}; e = (t&63) + 64r + 1024w ----
    {
        // e>>5 = ((t>>5)&1) + 2r + 32w ; slot bit1 ^= (t>>5)&1, bits2-3 ^= r&3
        const int b3b = (((t & 63) ^ (((t >> 5) & 1) << 1)) << 3) + ((t >> 6) << 13);
#pragma unroll
        for (int r = 0; r < 16; ++r)
            a[r] = *(const v2f*)(lds + ((b3b ^ ((r & 3) << 5)) + (r << 9)));
        apply_layer<1, 2, true>(a, CTV(6), SNV(6));
        apply_layer<2, 4, true>(a, CTV(7), SNV(7));
        apply_layer<4, 8, true>(a, CTV(8), SNV(8));
#pragma unroll
        for (int r = 0; r < 16; ++r)
            *(v2f*)(lds + ((b3b ^ ((r & 3) << 5)) + (r << 9))) = a[r];
    }
    __syncthreads();

    // ---- pass 4: layers 9..11 on idx bits {9,10,11,0}; e = 2t + 512k + b0 ----
    {
        // e>>5 = (t>>4) + 16k ; xor term depends only on t:
        // byte = (16t ^ (((t>>4)&7)<<4)) + 4096k ; (b0=0,b0=1) adjacent -> b128
        const int F0b = (t << 4) ^ (((t >> 4) & 7) << 4);
#pragma unroll
        for (int k = 0; k < 8; ++k) {
            const v4f v = *(const v4f*)(lds + (F0b + (k << 12)));
            v2f q0; q0.x = v.x; q0.y = v.y;
            v2f q1; q1.x = v.z; q1.y = v.w;
            a[k] = q0;       // bit0 = 0
            a[k + 8] = q1;   // bit0 = 1
        }
        apply_layer<1, 2, true >(a, CTV(9),  SNV(9));   // c=b9,  t=b10
        apply_layer<2, 4, true >(a, CTV(10), SNV(10));  // c=b10, t=b11
        apply_layer<4, 8, false>(a, CTV(11), SNV(11));  // c=b11, t=b0

        // probs epilogue; scale = 1/4096 (encode norm) * (1/sqrt2)^24 = 2^-24
        // folded as a single v_pk_mul per k; non-temporal 64 MB write stream.
        v2f sc2; sc2.x = 0x1p-24f; sc2.y = 0x1p-24f;
        v2f* outp = (v2f*)(out + sbase);
#pragma unroll
        for (int k = 0; k < 8; ++k) {
            const v2f q0 = a[k] * a[k];             // v_pk_mul_f32
            const v2f q1 = a[k | 8] * a[k | 8];
            v2f res; res.x = q0.x + q0.y;
            res.y = q1.x + q1.y;
            res = res * sc2;                        // v_pk_mul_f32
            __builtin_nontemporal_store(res, outp + t + (k << 8));
        }
    }
#undef CTV
#undef SNV
}

extern "C" void kernel_launch(void* const* d_in, const int* in_sizes, int n_in,
                              void* d_out, int out_size, void* d_ws, size_t ws_size,
                              hipStream_t stream) {
    (void)in_sizes; (void)n_in; (void)out_size; (void)d_ws; (void)ws_size;
    const float* state  = (const float*)d_in[0];   // (8,512,4096) fp32
    const float* params = (const float*)d_in[1];   // (12,) fp32
    float* out = (float*)d_out;                    // (8,512,4096) fp32
    qlayer_kernel<<<dim3(4096), dim3(TPB), 0, stream>>>(state, params, out);
}